// Round 1
// baseline (1095.153 us; speedup 1.0000x reference)
//
#include <hip/hip_runtime.h>

#define RELS 4
#define NGRAPH 256

static inline size_t alignup(size_t x) { return (x + 255) & ~(size_t)255; }

// ---------------------------------------------------------------------------
// Count edges per (dst, relation): cnt[dst*R + et] += 1
// ---------------------------------------------------------------------------
__global__ void count_kernel(const int* __restrict__ dst, const int* __restrict__ et,
                             float* __restrict__ cnt, int E)
{
    int e = blockIdx.x * blockDim.x + threadIdx.x;
    if (e < E) {
        unsafeAtomicAdd(&cnt[dst[e] * RELS + et[e]], 1.0f);
    }
}

// ---------------------------------------------------------------------------
// Scatter-add features into per-(node,relation) accumulator.
// Lane-per-channel: IN consecutive lanes handle one edge's IN channels,
// so atomic addresses are consecutive within each group (L2 locality).
// ---------------------------------------------------------------------------
template<int IN>
__global__ void scatter_kernel(const float* __restrict__ feat,
                               const int* __restrict__ src,
                               const int* __restrict__ dst,
                               const int* __restrict__ et,
                               float* __restrict__ s, int E)
{
    constexpr int SH = (IN == 16) ? 4 : 5;
    int i = blockIdx.x * blockDim.x + threadIdx.x;
    int total = E * IN;
    if (i >= total) return;
    int e = i >> SH;
    int k = i & (IN - 1);
    float v = feat[src[e] * IN + k];
    unsafeAtomicAdd(&s[(dst[e] * RELS + et[e]) * IN + k], v);
}

// ---------------------------------------------------------------------------
// Dense per-node transform:
//   out[i] = bias + hin[i] @ root + sum_r (s[i,r]/max(cnt[i,r],1)) @ W_r
// Optional ReLU; optional fused segment-max pool (monotone uint mapping +
// atomicMax) instead of storing hout.
// ---------------------------------------------------------------------------
template<int IN, int OUT, bool RELU, bool POOL>
__global__ __launch_bounds__(256)
void transform_kernel(const float* __restrict__ s, const float* __restrict__ cnt,
                      const float* __restrict__ hin,
                      const float* __restrict__ W, const float* __restrict__ root,
                      const float* __restrict__ bias,
                      float* __restrict__ hout, unsigned* __restrict__ gpool,
                      const int* __restrict__ batch, int n)
{
    constexpr int WSZ = RELS * IN * OUT;   // relation weights
    constexpr int RSZ = IN * OUT;          // root weights
    __shared__ float sW[WSZ + RSZ + OUT];
    for (int i = threadIdx.x; i < WSZ; i += 256) sW[i] = W[i];
    for (int i = threadIdx.x; i < RSZ; i += 256) sW[WSZ + i] = root[i];
    for (int i = threadIdx.x; i < OUT; i += 256) sW[WSZ + RSZ + i] = bias[i];
    __syncthreads();

    int node = blockIdx.x * 256 + threadIdx.x;
    if (node >= n) return;

    const float4* sWv = (const float4*)sW;
    float4 acc[OUT / 4];
    #pragma unroll
    for (int o = 0; o < OUT / 4; ++o) acc[o] = sWv[(WSZ + RSZ) / 4 + o];

    // root term: hin[node] @ root
    const float4* hv = (const float4*)(hin + (size_t)node * IN);
    #pragma unroll
    for (int k4 = 0; k4 < IN / 4; ++k4) {
        float4 xv = hv[k4];
        #pragma unroll
        for (int kk = 0; kk < 4; ++kk) {
            float x1 = (&xv.x)[kk];
            int k = k4 * 4 + kk;
            #pragma unroll
            for (int o = 0; o < OUT / 4; ++o) {
                float4 w = sWv[(WSZ + k * OUT) / 4 + o];
                acc[o].x += x1 * w.x; acc[o].y += x1 * w.y;
                acc[o].z += x1 * w.z; acc[o].w += x1 * w.w;
            }
        }
    }

    // relation terms
    #pragma unroll
    for (int r = 0; r < RELS; ++r) {
        float c = cnt[node * RELS + r];
        float nrm = 1.0f / fmaxf(c, 1.0f);
        const float4* sv = (const float4*)(s + ((size_t)node * RELS + r) * IN);
        #pragma unroll
        for (int k4 = 0; k4 < IN / 4; ++k4) {
            float4 mv = sv[k4];
            mv.x *= nrm; mv.y *= nrm; mv.z *= nrm; mv.w *= nrm;
            #pragma unroll
            for (int kk = 0; kk < 4; ++kk) {
                float m1 = (&mv.x)[kk];
                int k = k4 * 4 + kk;
                #pragma unroll
                for (int o = 0; o < OUT / 4; ++o) {
                    float4 w = sWv[((r * IN + k) * OUT) / 4 + o];
                    acc[o].x += m1 * w.x; acc[o].y += m1 * w.y;
                    acc[o].z += m1 * w.z; acc[o].w += m1 * w.w;
                }
            }
        }
    }

    if (RELU) {
        #pragma unroll
        for (int o = 0; o < OUT / 4; ++o) {
            acc[o].x = fmaxf(acc[o].x, 0.f); acc[o].y = fmaxf(acc[o].y, 0.f);
            acc[o].z = fmaxf(acc[o].z, 0.f); acc[o].w = fmaxf(acc[o].w, 0.f);
        }
    }

    if (!POOL) {
        float4* ho = (float4*)(hout + (size_t)node * OUT);
        #pragma unroll
        for (int o = 0; o < OUT / 4; ++o) ho[o] = acc[o];
    } else {
        int g = batch[node];
        #pragma unroll
        for (int o = 0; o < OUT / 4; ++o) {
            #pragma unroll
            for (int kk = 0; kk < 4; ++kk) {
                float f = (&acc[o].x)[kk];
                unsigned u = __float_as_uint(f);
                u = (u & 0x80000000u) ? ~u : (u | 0x80000000u);
                atomicMax(&gpool[g * OUT + o * 4 + kk], u);
            }
        }
    }
}

// ---------------------------------------------------------------------------
// MLP head: [G,64] -> 128 (relu) -> 256 (relu) -> 51 -> softmax. 1 block/graph.
// ---------------------------------------------------------------------------
__global__ __launch_bounds__(256)
void mlp_kernel(const unsigned* __restrict__ gpool,
                const float* __restrict__ Wf1, const float* __restrict__ bf1,
                const float* __restrict__ Wh,  const float* __restrict__ bh,
                const float* __restrict__ Wl,  const float* __restrict__ bl,
                float* __restrict__ out)
{
    __shared__ float gin[64];
    __shared__ float f1[128];
    __shared__ float f2[256];
    __shared__ float lg[51];
    int g = blockIdx.x, t = threadIdx.x;

    if (t < 64) {
        unsigned u = gpool[g * 64 + t];
        u = (u & 0x80000000u) ? (u ^ 0x80000000u) : ~u;   // unmap
        gin[t] = __uint_as_float(u);
    }
    __syncthreads();

    if (t < 128) {
        float a = bf1[t];
        #pragma unroll 8
        for (int k = 0; k < 64; ++k) a += gin[k] * Wf1[k * 128 + t];
        f1[t] = fmaxf(a, 0.f);
    }
    __syncthreads();

    {
        float a = bh[t];
        #pragma unroll 8
        for (int k = 0; k < 128; ++k) a += f1[k] * Wh[k * 256 + t];
        f2[t] = fmaxf(a, 0.f);
    }
    __syncthreads();

    if (t < 51) {
        float a = bl[t];
        #pragma unroll 8
        for (int k = 0; k < 256; ++k) a += f2[k] * Wl[k * 51 + t];
        lg[t] = a;
    }
    __syncthreads();

    if (t == 0) {
        float m = lg[0];
        for (int i = 1; i < 51; ++i) m = fmaxf(m, lg[i]);
        float ssum = 0.f;
        for (int i = 0; i < 51; ++i) { float e = __expf(lg[i] - m); lg[i] = e; ssum += e; }
        float inv = 1.0f / ssum;
        for (int i = 0; i < 51; ++i) out[g * 51 + i] = lg[i] * inv;
    }
}

// ---------------------------------------------------------------------------
extern "C" void kernel_launch(void* const* d_in, const int* in_sizes, int n_in,
                              void* d_out, int out_size, void* d_ws, size_t ws_size,
                              hipStream_t stream)
{
    const float* x    = (const float*)d_in[0];
    const int*   ei   = (const int*)d_in[1];
    const int*   et   = (const int*)d_in[2];
    const int*   batch= (const int*)d_in[3];
    const float* W1   = (const float*)d_in[4];
    const float* r1   = (const float*)d_in[5];
    const float* b1   = (const float*)d_in[6];
    const float* W2   = (const float*)d_in[7];
    const float* r2   = (const float*)d_in[8];
    const float* b2   = (const float*)d_in[9];
    const float* W3   = (const float*)d_in[10];
    const float* r3   = (const float*)d_in[11];
    const float* b3   = (const float*)d_in[12];
    const float* Wf1  = (const float*)d_in[13];
    const float* bf1  = (const float*)d_in[14];
    const float* Wh   = (const float*)d_in[15];
    const float* bh   = (const float*)d_in[16];
    const float* Wl   = (const float*)d_in[17];
    const float* bl   = (const float*)d_in[18];

    const int N = in_sizes[0] / 16;
    const int E = in_sizes[2];
    const int* srcp = ei;
    const int* dstp = ei + E;

    char* ws = (char*)d_ws;
    size_t off = 0;
    float*    s     = (float*)(ws + off);   off += alignup((size_t)N * RELS * 32 * 4);
    float*    cnt   = (float*)(ws + off);   off += alignup((size_t)N * RELS * 4);
    float*    h1    = (float*)(ws + off);   off += alignup((size_t)N * 16 * 4);
    float*    h2    = (float*)(ws + off);   off += alignup((size_t)N * 32 * 4);
    unsigned* gpool = (unsigned*)(ws + off); off += alignup((size_t)NGRAPH * 64 * 4);
    (void)ws_size; (void)n_in; (void)out_size;

    // zero accumulators (stream-ordered, capture-safe)
    hipMemsetAsync(cnt, 0, (size_t)N * RELS * 4, stream);
    hipMemsetAsync(gpool, 0, (size_t)NGRAPH * 64 * 4, stream);
    hipMemsetAsync(s, 0, (size_t)N * RELS * 16 * 4, stream);

    count_kernel<<<(E + 255) / 256, 256, 0, stream>>>(dstp, et, cnt, E);

    // ---- layer 1: 16 -> 16, relu
    scatter_kernel<16><<<(E * 16 + 255) / 256, 256, 0, stream>>>(x, srcp, dstp, et, s, E);
    transform_kernel<16, 16, true, false><<<(N + 255) / 256, 256, 0, stream>>>(
        s, cnt, x, W1, r1, b1, h1, nullptr, nullptr, N);

    // ---- layer 2: 16 -> 32, relu
    hipMemsetAsync(s, 0, (size_t)N * RELS * 16 * 4, stream);
    scatter_kernel<16><<<(E * 16 + 255) / 256, 256, 0, stream>>>(h1, srcp, dstp, et, s, E);
    transform_kernel<16, 32, true, false><<<(N + 255) / 256, 256, 0, stream>>>(
        s, cnt, h1, W2, r2, b2, h2, nullptr, nullptr, N);

    // ---- layer 3: 32 -> 64, no relu, fused max-pool
    hipMemsetAsync(s, 0, (size_t)N * RELS * 32 * 4, stream);
    scatter_kernel<32><<<(E * 32 + 255) / 256, 256, 0, stream>>>(h2, srcp, dstp, et, s, E);
    transform_kernel<32, 64, false, true><<<(N + 255) / 256, 256, 0, stream>>>(
        s, cnt, h2, W3, r3, b3, nullptr, gpool, batch, N);

    // ---- MLP head + softmax
    mlp_kernel<<<NGRAPH, 256, 0, stream>>>(gpool, Wf1, bf1, Wh, bh, Wl, bl, (float*)d_out);
}